// Round 17
// baseline (625.760 us; speedup 1.0000x reference)
//
#include <hip/hip_runtime.h>
#include <hip/hip_fp16.h>

#define DEV __device__ __forceinline__

typedef _Float16 f16x8 __attribute__((ext_vector_type(8)));
typedef float f32x4 __attribute__((ext_vector_type(4)));

DEV float mask_val(const unsigned char* mb, int n) {
  // Detect train_mask storage from its first element: uint8 bool / int32 / float32.
  unsigned b0 = mb[0], b1 = mb[1], b2 = mb[2], b3 = mb[3];
  if (b0 <= 1u && b1 == b0 && b2 == b0 && b3 == b0) {
    return mb[n] ? 1.f : 0.f;                       // 1-byte bool
  } else if (b1 == 0u && b2 == 0u && b3 == 0u) {
    return ((const int*)mb)[n] ? 1.f : 0.f;         // int32
  } else {
    return (((const float*)mb)[n] != 0.f) ? 1.f : 0.f; // float32
  }
}

// butterfly sum across each 32-lane half via ds_swizzle (LDS pipe — overlaps the busy VALU)
DEV float head_sum32(float x) {
  x += __int_as_float(__builtin_amdgcn_ds_swizzle(__float_as_int(x), 0x041F));  // xor 1
  x += __int_as_float(__builtin_amdgcn_ds_swizzle(__float_as_int(x), 0x081F));  // xor 2
  x += __int_as_float(__builtin_amdgcn_ds_swizzle(__float_as_int(x), 0x101F));  // xor 4
  x += __int_as_float(__builtin_amdgcn_ds_swizzle(__float_as_int(x), 0x201F));  // xor 8
  x += __int_as_float(__builtin_amdgcn_ds_swizzle(__float_as_int(x), 0x401F));  // xor 16
  return x;
}

// ---------------- K0: fused setup — cbuf rank-1 collapses + fp16 weight transpose ----------------
__global__ __launch_bounds__(256) void k_setup(
    const float* __restrict__ tf_w, const float* __restrict__ tf_b,
    const float* __restrict__ deg_w, const float* __restrict__ deg_b,
    const float* __restrict__ wenc_w, const float* __restrict__ wenc_b,
    const float* __restrict__ comb_w,
    const float* __restrict__ lin_w, const float* __restrict__ Wq,
    const float* __restrict__ Wk, const float* __restrict__ Wv,
    const float* __restrict__ Wsk,
    float* __restrict__ cbuf, _Float16* __restrict__ wt) {
  if (blockIdx.x < 80) {
    const float* Ws[5] = {lin_w, Wq, Wk, Wv, Wsk};
    int idx = blockIdx.x * 256 + threadIdx.x;
    if (idx < 5 * 4096) {
      int s = idx >> 12, r = idx & 4095;
      int j = r >> 6, c = r & 63;
      wt[(s << 12) + c * 64 + j] = (_Float16)Ws[s][j * 64 + c];
    }
  } else if (threadIdx.x < 64) {
    int c = threadIdx.x;
    float A0 = 0, B0 = 0, A1 = 0, B1 = 0, P0 = 0, Q0 = 0, P1 = 0, Q1 = 0;
    for (int j = 0; j < 64; ++j) {
      float w  = wenc_w[j * 64 + c];
      float cw = comb_w[(64 + j) * 64 + c];
      float twj = tf_w[j], tbj = tf_b[j], dwj = deg_w[j], dbj = deg_b[j];
      A0 += twj * w;  B0 += tbj * w;
      A1 += dwj * w;  B1 += dbj * w;
      P0 += twj * cw; Q0 += tbj * cw;
      P1 += dwj * cw; Q1 += dbj * cw;
    }
    float wb = wenc_b[c];
    cbuf[c]       = A0; cbuf[64 + c]  = B0 + wb;
    cbuf[128 + c] = A1; cbuf[192 + c] = B1 + wb;
    cbuf[256 + c] = P0; cbuf[320 + c] = Q0;
    cbuf[384 + c] = P1; cbuf[448 + c] = Q1;
  }
}

// ---------------- K1: MFMA node projections (layouts verified in-session R8) ----------------
__global__ __launch_bounds__(256) void k_node_proj(
    const float* __restrict__ x, const _Float16* __restrict__ wt,
    const float* __restrict__ lin_b, const float* __restrict__ bq,
    const float* __restrict__ bk, const float* __restrict__ bv,
    const float* __restrict__ bsk, const float* __restrict__ be,
    float* __restrict__ q, __half2* __restrict__ kvp,
    float* __restrict__ skipout, int N) {
  __shared__ _Float16 H[4][16 * 72];
  const int tid = threadIdx.x;
  const int lane = tid & 63;
  const int wv = tid >> 6;
  const int mrow = lane & 15;
  const int kgrp = lane >> 4;
  const float invs = 0.17677669529663687f;  // 1/sqrt(32)
  float b_lin[4], b_q[4], b_k[4], b_v[4], b_sk[4];
#pragma unroll
  for (int nt = 0; nt < 4; ++nt) {
    const int cc = nt * 16 + mrow;
    b_lin[nt] = lin_b[cc];
    b_q[nt] = bq[cc];
    b_k[nt] = bk[cc] + be[cc];
    b_v[nt] = bv[cc] + be[cc];
    b_sk[nt] = bsk[cc];
  }
  _Float16* Hw = H[wv];
  const int ntiles = (N + 63) >> 6;
  for (int tile = blockIdx.x; tile < ntiles; tile += gridDim.x) {
    const int base = tile << 6;
    const int rowA = base + wv * 16 + mrow;
    const int rclamp = (rowA < N) ? rowA : (N - 1);
    const float* xr = x + (size_t)rclamp * 64 + kgrp * 8;
    const float4 u0 = *(const float4*)xr;
    const float4 u1 = *(const float4*)(xr + 4);
    const float4 u2 = *(const float4*)(xr + 32);
    const float4 u3 = *(const float4*)(xr + 36);
    const f16x8 a0 = {(_Float16)u0.x, (_Float16)u0.y, (_Float16)u0.z, (_Float16)u0.w,
                      (_Float16)u1.x, (_Float16)u1.y, (_Float16)u1.z, (_Float16)u1.w};
    const f16x8 a1 = {(_Float16)u2.x, (_Float16)u2.y, (_Float16)u2.z, (_Float16)u2.w,
                      (_Float16)u3.x, (_Float16)u3.y, (_Float16)u3.z, (_Float16)u3.w};
#pragma unroll
    for (int nt = 0; nt < 4; ++nt) {
      const _Float16* wb0 = wt + (nt * 16 + mrow) * 64 + kgrp * 8;
      const f16x8 B0 = *(const f16x8*)wb0;
      const f16x8 B1 = *(const f16x8*)(wb0 + 32);
      f32x4 C = {0.f, 0.f, 0.f, 0.f};
      C = __builtin_amdgcn_mfma_f32_16x16x32_f16(a0, B0, C, 0, 0, 0);
      C = __builtin_amdgcn_mfma_f32_16x16x32_f16(a1, B1, C, 0, 0, 0);
#pragma unroll
      for (int r = 0; r < 4; ++r) {
        const float hval = fmaxf(C[r] + b_lin[nt], 0.f);
        Hw[(kgrp * 4 + r) * 72 + nt * 16 + mrow] = (_Float16)hval;
      }
    }
    const f16x8 ha0 = *(const f16x8*)(Hw + mrow * 72 + kgrp * 8);
    const f16x8 ha1 = *(const f16x8*)(Hw + mrow * 72 + 32 + kgrp * 8);
    const int orow0 = base + wv * 16 + kgrp * 4;
#pragma unroll
    for (int nt = 0; nt < 4; ++nt) {
      const _Float16* wb0 = wt + 4096 + (nt * 16 + mrow) * 64 + kgrp * 8;
      const f16x8 B0 = *(const f16x8*)wb0;
      const f16x8 B1 = *(const f16x8*)(wb0 + 32);
      f32x4 C = {0.f, 0.f, 0.f, 0.f};
      C = __builtin_amdgcn_mfma_f32_16x16x32_f16(ha0, B0, C, 0, 0, 0);
      C = __builtin_amdgcn_mfma_f32_16x16x32_f16(ha1, B1, C, 0, 0, 0);
#pragma unroll
      for (int r = 0; r < 4; ++r) {
        const int orow = orow0 + r;
        if (orow < N) q[(size_t)orow * 64 + nt * 16 + mrow] = (C[r] + b_q[nt]) * invs;
      }
    }
#pragma unroll
    for (int nt = 0; nt < 4; ++nt) {
      const _Float16* wk0 = wt + 2 * 4096 + (nt * 16 + mrow) * 64 + kgrp * 8;
      const _Float16* wv0 = wt + 3 * 4096 + (nt * 16 + mrow) * 64 + kgrp * 8;
      const f16x8 Bk0 = *(const f16x8*)wk0;
      const f16x8 Bk1 = *(const f16x8*)(wk0 + 32);
      const f16x8 Bv0 = *(const f16x8*)wv0;
      const f16x8 Bv1 = *(const f16x8*)(wv0 + 32);
      f32x4 Ck = {0.f, 0.f, 0.f, 0.f};
      f32x4 Cv = {0.f, 0.f, 0.f, 0.f};
      Ck = __builtin_amdgcn_mfma_f32_16x16x32_f16(ha0, Bk0, Ck, 0, 0, 0);
      Ck = __builtin_amdgcn_mfma_f32_16x16x32_f16(ha1, Bk1, Ck, 0, 0, 0);
      Cv = __builtin_amdgcn_mfma_f32_16x16x32_f16(ha0, Bv0, Cv, 0, 0, 0);
      Cv = __builtin_amdgcn_mfma_f32_16x16x32_f16(ha1, Bv1, Cv, 0, 0, 0);
#pragma unroll
      for (int r = 0; r < 4; ++r) {
        const int orow = orow0 + r;
        if (orow < N)
          kvp[(size_t)orow * 64 + nt * 16 + mrow] =
              __halves2half2(__float2half_rn(Ck[r] + b_k[nt]), __float2half_rn(Cv[r] + b_v[nt]));
      }
    }
#pragma unroll
    for (int nt = 0; nt < 4; ++nt) {
      const _Float16* wb0 = wt + 4 * 4096 + (nt * 16 + mrow) * 64 + kgrp * 8;
      const f16x8 B0 = *(const f16x8*)wb0;
      const f16x8 B1 = *(const f16x8*)(wb0 + 32);
      f32x4 C = {0.f, 0.f, 0.f, 0.f};
      C = __builtin_amdgcn_mfma_f32_16x16x32_f16(ha0, B0, C, 0, 0, 0);
      C = __builtin_amdgcn_mfma_f32_16x16x32_f16(ha1, B1, C, 0, 0, 0);
#pragma unroll
      for (int r = 0; r < 4; ++r) {
        const int orow = orow0 + r;
        if (orow < N) skipout[(size_t)orow * 64 + nt * 16 + mrow] = C[r] + b_sk[nt];
      }
    }
  }
}

// ---------------- CSR build ----------------
__global__ __launch_bounds__(256) void k_hist(const int* __restrict__ ei, int* __restrict__ counts,
                                              int* __restrict__ rank, int E) {
  int i = blockIdx.x * 256 + threadIdx.x;
  if (i < E) rank[i] = atomicAdd(&counts[ei[E + i]], 1);
}

__global__ __launch_bounds__(256) void k_scan1(const int* __restrict__ counts, int* __restrict__ excl,
                                               int* __restrict__ bsum, int N) {
  __shared__ int s[256];
  const int t = threadIdx.x;
  const int idx = blockIdx.x * 256 + t;
  int val = (idx < N) ? counts[idx] : 0;
  s[t] = val;
  __syncthreads();
  for (int d = 1; d < 256; d <<= 1) {
    int add = (t >= d) ? s[t - d] : 0;
    __syncthreads();
    s[t] += add;
    __syncthreads();
  }
  if (idx < N) excl[idx] = s[t] - val;
  if (t == 255) bsum[blockIdx.x] = s[255];
}

__global__ __launch_bounds__(1024) void k_scan2(int* __restrict__ bsum, int B) {
  __shared__ int sm[1024];
  const int t = threadIdx.x;
  if (B <= 1024) {
    int val = (t < B) ? bsum[t] : 0;
    sm[t] = val;
    __syncthreads();
    for (int d = 1; d < 1024; d <<= 1) {
      int add = (t >= d) ? sm[t - d] : 0;
      __syncthreads();
      sm[t] += add;
      __syncthreads();
    }
    if (t < B) bsum[t] = sm[t] - val;  // exclusive
  } else if (t == 0) {
    int acc = 0;
    for (int i = 0; i < B; ++i) { int tt = bsum[i]; bsum[i] = acc; acc += tt; }
  }
}

__global__ __launch_bounds__(256) void k_scan3(const int* __restrict__ bsum, int* __restrict__ rowptr,
                                               int N, int E) {
  int i = blockIdx.x * 256 + threadIdx.x;
  if (i < N) rowptr[i] = rowptr[i] + bsum[i >> 8];
  if (i == 0) rowptr[N] = E;
}

__global__ __launch_bounds__(256) void k_fill(const int* __restrict__ ei,
                                              const float* __restrict__ node_time,
                                              const float* __restrict__ edge_time,
                                              const int* __restrict__ rowptr,
                                              const int* __restrict__ rank,
                                              int2* __restrict__ er, int E) {
  int e = blockIdx.x * 256 + threadIdx.x;
  if (e < E) {
    int s = ei[e], d = ei[E + e];
    int pos = rowptr[d] + rank[e];
    er[pos] = make_int2(s, __float_as_int(node_time[s] - edge_time[e]));
  }
}

// ---------------- K2: CSR aggregate — R8 structure, forced 8 blocks/CU (VGPR<=64) ----------------
// rv packed as half2[8] (fp16 rv ~ same precision class as fp16 kv) to fit the 64-VGPR budget.
__global__ __launch_bounds__(256, 8) void k_aggregate(
    const int* __restrict__ rowptr, const int2* __restrict__ er,
    const float* __restrict__ q, const unsigned* __restrict__ kvu,
    const float* __restrict__ time_w, const float* __restrict__ time_b,
    const float* __restrict__ We,
    float* __restrict__ h1, int N) {
  __shared__ float swS[4][64];
  __shared__ float EAs[4][2][16];
  const int tid = threadIdx.x;
  const int c = tid & 63;
  const int wv = tid >> 6;
  const float INV2PI = 0.15915494309189535f;
  float wcol[32], Gw[32];
#pragma unroll
  for (int j = 0; j < 32; ++j) wcol[j] = We[j * 64 + c];
#pragma unroll
  for (int j = 0; j < 32; ++j) Gw[j] = We[(c & 31) * 64 + (c & 32) + j];
  const float tw = time_w[c & 31] * INV2PI;
  const float tb = time_b[c & 31] * INV2PI;
  const int h32 = c & 32;
  const int lc = c & 15;
  const bool writer = (c & 16) == 0;  // lanes 0-15 (head0) and 32-47 (head1)
  float (*eaF)[16] = EAs[wv];
  const int n0 = blockIdx.x * 4 + wv;
  const int nstride = gridDim.x * 4;
  for (int n = n0; n < N; n += nstride) {
    const int start = __builtin_amdgcn_readfirstlane(rowptr[n]);
    const int end = __builtin_amdgcn_readfirstlane(rowptr[n + 1]);
    const float skipv = h1[(size_t)n * 64 + c];  // prefetch staged skip early
    const float qc = q[(size_t)n * 64 + c];      // pre-scaled by 1/sqrt(32)
    swS[wv][c] = qc;
    float Gc = 0.f;
#pragma unroll
    for (int j = 0; j < 32; ++j) Gc = fmaf(swS[wv][h32 | j], Gw[j], Gc);
    float m = -1e30f, den = 0.f, num = 0.f, S = 0.f;
    for (int ce = start; ce < end; ce += 16) {
      const int cnt = (end - ce < 16) ? (end - ce) : 16;
      // ---- issue phase: 16 er loads + 16 coalesced kv gathers, all in flight ----
      int src_[16];
      float rr_[16];
#pragma unroll
      for (int i = 0; i < 16; ++i) {
        const int ee = ce + ((i < cnt) ? i : cnt - 1);
        const int2 a = er[ee];
        src_[i] = a.x;
        rr_[i] = __int_as_float(a.y);
      }
      unsigned kvr[16];
#pragma unroll
      for (int i = 0; i < 16; ++i) kvr[i] = kvu[(unsigned)(src_[i] * 64 + c)];
      // ---- pass 1: rv (packed half2) + 16 partial products + swizzle butterflies ----
      __half2 rvh[8];
      float p[16];
#pragma unroll
      for (int i = 0; i < 16; i += 2) {
        float a0 = fmaf(rr_[i], tw, tb);
        a0 = a0 - floorf(a0);
        const float rv0 = __builtin_amdgcn_cosf(a0);
        float a1 = fmaf(rr_[i + 1], tw, tb);
        a1 = a1 - floorf(a1);
        const float rv1 = __builtin_amdgcn_cosf(a1);
        rvh[i >> 1] = __halves2half2(__float2half_rn(rv0), __float2half_rn(rv1));
        const __half2 h0 = *(const __half2*)&kvr[i];
        const __half2 h1v = *(const __half2*)&kvr[i + 1];
        p[i] = fmaf(rv0, Gc, qc * __half2float(h0.x));
        p[i + 1] = fmaf(rv1, Gc, qc * __half2float(h1v.x));
      }
#pragma unroll
      for (int i = 0; i < 16; ++i) p[i] = head_sum32(p[i]);
#pragma unroll
      for (int i = 0; i < 16; ++i)
        if (i >= cnt) p[i] = -1e30f;           // mask padded duplicates (-> ea = exact 0)
      // ---- fold chunk max, rescale state once ----
      float cm = p[0];
#pragma unroll
      for (int i = 1; i < 16; ++i) cm = fmaxf(cm, p[i]);
      const float mn = fmaxf(m, cm);
      const float sc = __expf(m - mn);
      num *= sc; den *= sc; S *= sc; m = mn;
      // ---- exp dedup: writer lanes compute ONE exp each (static select), LDS broadcast ----
      if (writer) {
        float pv = p[0];
#pragma unroll
        for (int i = 1; i < 16; ++i) pv = (lc == i) ? p[i] : pv;
        eaF[c >> 5][lc] = __expf(pv - m);
      }
      const float* eah = eaF[h32 ? 1 : 0];
      const float4 e0 = ((const float4*)eah)[0];
      const float4 e1 = ((const float4*)eah)[1];
      const float4 e2 = ((const float4*)eah)[2];
      const float4 e3 = ((const float4*)eah)[3];
      const float ea_[16] = {e0.x, e0.y, e0.z, e0.w, e1.x, e1.y, e1.z, e1.w,
                             e2.x, e2.y, e2.z, e2.w, e3.x, e3.y, e3.z, e3.w};
      // ---- pass 2: branchless accumulate (padded ea are exact zeros) ----
#pragma unroll
      for (int i = 0; i < 16; ++i) {
        const float eai = ea_[i];
        const __half2 h2 = *(const __half2*)&kvr[i];
        const __half2 rp = rvh[i >> 1];
        const float rvi = (i & 1) ? __half2float(rp.y) : __half2float(rp.x);
        num = fmaf(eai, __half2float(h2.y), num);
        S = fmaf(eai, rvi, S);
        den += eai;
      }
    }
    // e-projection contribution: econ[c] = sum_j We[j,c] * S[h32 + j]
    swS[wv][c] = S;
    float econ = 0.f;
#pragma unroll
    for (int j = 0; j < 32; ++j) econ = fmaf(swS[wv][h32 | j], wcol[j], econ);
    const float agg = (num + econ) / (den + 1e-16f);
    h1[(size_t)n * 64 + c] = agg + skipv;
  }
}

// ---------------- K4: epilogue (context attention + combine + out + log_softmax) ----------------
__global__ __launch_bounds__(256) void k_epilogue(
    const float* __restrict__ t_int, const float* __restrict__ deg,
    const float* __restrict__ cbuf,
    const float* __restrict__ wx_w, const float* __restrict__ wx_b,
    const float* __restrict__ comb_w, const float* __restrict__ comb_b,
    const float* __restrict__ out_w, const float* __restrict__ out_b,
    const int* __restrict__ y, const unsigned char* __restrict__ maskb,
    float* __restrict__ out, int N) {
  __shared__ float sh[4][64];
  const int tid = threadIdx.x;
  const int c = tid & 63;
  const int wv = tid >> 6;
  float wxreg[64], cbreg[64];
#pragma unroll
  for (int j = 0; j < 64; ++j) { wxreg[j] = wx_w[j * 64 + c]; cbreg[j] = comb_w[j * 64 + c]; }
  const float A0 = cbuf[c], B0 = cbuf[64 + c], A1 = cbuf[128 + c], B1 = cbuf[192 + c];
  const float P0 = cbuf[256 + c], Q0 = cbuf[320 + c], P1 = cbuf[384 + c], Q1 = cbuf[448 + c];
  const float wxb = wx_b[c], cbb = comb_b[c];
  const float ow0 = out_w[c * 2 + 0], ow1 = out_w[c * 2 + 1];
  const float ob0 = out_b[0], ob1 = out_b[1];
  const size_t O1 = (size_t)N * 64;
  const size_t O2 = O1 + (size_t)N * 2;
  const size_t O3 = O2 + (size_t)N;
  const int ngroups = (N + 3) >> 2;
  for (int g = blockIdx.x; g < ngroups; g += gridDim.x) {
    const int n = g * 4 + wv;
    const bool act = n < N;
    float h1a = 0.f, ti = 0.f, dg = 0.f;
    if (act) {
      h1a = out[(size_t)n * 64 + c];
      ti = t_int[n];
      dg = deg[n];
    }
    sh[wv][c] = h1a;
    const float4* hr = (const float4*)&sh[wv][0];
    float xp = wxb;
    float acc = cbb;
#pragma unroll
    for (int j4 = 0; j4 < 16; ++j4) {
      float4 hv = hr[j4];
      xp  = fmaf(hv.x, wxreg[4 * j4 + 0], xp);
      xp  = fmaf(hv.y, wxreg[4 * j4 + 1], xp);
      xp  = fmaf(hv.z, wxreg[4 * j4 + 2], xp);
      xp  = fmaf(hv.w, wxreg[4 * j4 + 3], xp);
      acc = fmaf(hv.x, cbreg[4 * j4 + 0], acc);
      acc = fmaf(hv.y, cbreg[4 * j4 + 1], acc);
      acc = fmaf(hv.z, cbreg[4 * j4 + 2], acc);
      acc = fmaf(hv.w, cbreg[4 * j4 + 3], acc);
    }
    xp = tanhf(xp);
    const float ep0 = tanhf(fmaf(ti, A0, B0));
    const float ep1 = tanhf(fmaf(dg, A1, B1));
    float d0 = ep0 * xp, d1 = ep1 * xp;
#pragma unroll
    for (int msk = 32; msk >= 1; msk >>= 1) { d0 += __shfl_xor(d0, msk, 64); d1 += __shfl_xor(d1, msk, 64); }
    const float mx = fmaxf(d0, d1);
    const float e0 = expf(d0 - mx), e1 = expf(d1 - mx);
    const float sden = e0 + e1;
    const float s0 = e0 / sden, s1 = e1 / sden;
    acc = fmaf(s0, fmaf(ti, P0, Q0), acc);
    acc = fmaf(s1, fmaf(dg, P1, Q1), acc);
    float z0 = acc * ow0, z1 = acc * ow1;
#pragma unroll
    for (int msk = 32; msk >= 1; msk >>= 1) { z0 += __shfl_xor(z0, msk, 64); z1 += __shfl_xor(z1, msk, 64); }
    if (act) {
      out[(size_t)n * 64 + c] = acc;
      if (c == 0) {
        z0 += ob0; z1 += ob1;
        const float mz = fmaxf(z0, z1);
        const float lse = mz + logf(expf(z0 - mz) + expf(z1 - mz));
        out[O1 + (size_t)n * 2 + 0] = z0 - lse;
        out[O1 + (size_t)n * 2 + 1] = z1 - lse;
        out[O2 + (size_t)n] = (float)y[n];
        out[O3 + (size_t)n] = mask_val(maskb, n);
      }
    }
  }
}

extern "C" void kernel_launch(void* const* d_in, const int* in_sizes, int n_in,
                              void* d_out, int out_size, void* d_ws, size_t ws_size,
                              hipStream_t stream) {
  const float* x          = (const float*)d_in[0];
  const int*   ei         = (const int*)d_in[1];
  const float* node_time  = (const float*)d_in[2];
  const float* edge_time  = (const float*)d_in[3];
  const float* nmoti      = (const float*)d_in[4];
  const float* nod        = (const float*)d_in[5];
  const int*   y          = (const int*)d_in[6];
  const unsigned char* mask = (const unsigned char*)d_in[7];
  const float* time_w = (const float*)d_in[8];
  const float* time_b = (const float*)d_in[9];
  const float* tf_w   = (const float*)d_in[10];
  const float* tf_b   = (const float*)d_in[11];
  const float* deg_w  = (const float*)d_in[12];
  const float* deg_b  = (const float*)d_in[13];
  const float* lin_w  = (const float*)d_in[14];
  const float* lin_b  = (const float*)d_in[15];
  const float* Wq     = (const float*)d_in[16];
  const float* bq     = (const float*)d_in[17];
  const float* Wk     = (const float*)d_in[18];
  const float* bk     = (const float*)d_in[19];
  const float* Wv     = (const float*)d_in[20];
  const float* bv     = (const float*)d_in[21];
  const float* We     = (const float*)d_in[22];
  const float* be     = (const float*)d_in[23];
  const float* Wsk    = (const float*)d_in[24];
  const float* bsk    = (const float*)d_in[25];
  const float* wenc_w = (const float*)d_in[26];
  const float* wenc_b = (const float*)d_in[27];
  const float* wx_w   = (const float*)d_in[28];
  const float* wx_b   = (const float*)d_in[29];
  const float* comb_w = (const float*)d_in[30];
  const float* comb_b = (const float*)d_in[31];
  const float* out_w  = (const float*)d_in[32];
  const float* out_b  = (const float*)d_in[33];

  const int N = in_sizes[2];   // node_time
  const int E = in_sizes[3];   // edge_time
  const size_t N64 = (size_t)N * 64;

  float*    q    = (float*)d_ws;
  __half2*  kvp  = (__half2*)(q + N64);       // N64 half2 = N64 * 4B
  int2*     er   = (int2*)((char*)kvp + N64 * sizeof(__half2));
  int*      rank = (int*)(er + E);            // E ints
  int*      counts = rank + E;
  int*      rowptr = counts + N;              // N+1 ints
  int*      bsum   = rowptr + N + 1;          // ceil(N/256) ints (padded)
  float*    cbuf   = (float*)(bsum + 4096);
  _Float16* wt     = (_Float16*)(cbuf + 512); // 5 * 4096 fp16
  float*    outf   = (float*)d_out;
  float*    skip   = outf;  // stage skip in d_out[0:N*64)

  const int B = (N + 255) / 256;

  hipMemsetAsync(counts, 0, (size_t)N * sizeof(int), stream);

  k_setup<<<81, 256, 0, stream>>>(tf_w, tf_b, deg_w, deg_b, wenc_w, wenc_b, comb_w,
                                  lin_w, Wq, Wk, Wv, Wsk, cbuf, wt);

  const int ntiles = (N + 63) >> 6;
  k_node_proj<<<ntiles, 256, 0, stream>>>(x, wt, lin_b, bq, bk, bv, bsk, be,
                                          q, kvp, skip, N);

  const int EB = (E + 255) / 256;
  k_hist<<<EB, 256, 0, stream>>>(ei, counts, rank, E);
  k_scan1<<<B, 256, 0, stream>>>(counts, rowptr, bsum, N);
  k_scan2<<<1, 1024, 0, stream>>>(bsum, B);
  k_scan3<<<B, 256, 0, stream>>>(bsum, rowptr, N, E);
  k_fill<<<EB, 256, 0, stream>>>(ei, node_time, edge_time, rowptr, rank, er, E);

  // persistent grid: 2048 blocks = 8 blocks/CU (32 waves/CU; VGPR forced <= 64)
  int agb = 2048;
  if (agb > (N + 3) / 4) agb = (N + 3) / 4;
  k_aggregate<<<agb, 256, 0, stream>>>(rowptr, er, q, (const unsigned*)kvp,
                                       time_w, time_b, We, outf, N);

  k_epilogue<<<2048, 256, 0, stream>>>(nmoti, nod, cbuf, wx_w, wx_b,
                                       comb_w, comb_b, out_w, out_b, y, mask, outf, N);
}

// Round 18
// 357.898 us; speedup vs baseline: 1.7484x; 1.7484x over previous
//
#include <hip/hip_runtime.h>
#include <hip/hip_fp16.h>

#define DEV __device__ __forceinline__

typedef _Float16 f16x8 __attribute__((ext_vector_type(8)));
typedef float f32x4 __attribute__((ext_vector_type(4)));

DEV float mask_val(const unsigned char* mb, int n) {
  // Detect train_mask storage from its first element: uint8 bool / int32 / float32.
  unsigned b0 = mb[0], b1 = mb[1], b2 = mb[2], b3 = mb[3];
  if (b0 <= 1u && b1 == b0 && b2 == b0 && b3 == b0) {
    return mb[n] ? 1.f : 0.f;                       // 1-byte bool
  } else if (b1 == 0u && b2 == 0u && b3 == 0u) {
    return ((const int*)mb)[n] ? 1.f : 0.f;         // int32
  } else {
    return (((const float*)mb)[n] != 0.f) ? 1.f : 0.f; // float32
  }
}

// butterfly sum across each 32-lane half via ds_swizzle (LDS pipe — overlaps the busy VALU)
DEV float head_sum32(float x) {
  x += __int_as_float(__builtin_amdgcn_ds_swizzle(__float_as_int(x), 0x041F));  // xor 1
  x += __int_as_float(__builtin_amdgcn_ds_swizzle(__float_as_int(x), 0x081F));  // xor 2
  x += __int_as_float(__builtin_amdgcn_ds_swizzle(__float_as_int(x), 0x101F));  // xor 4
  x += __int_as_float(__builtin_amdgcn_ds_swizzle(__float_as_int(x), 0x201F));  // xor 8
  x += __int_as_float(__builtin_amdgcn_ds_swizzle(__float_as_int(x), 0x401F));  // xor 16
  return x;
}

// ---------------- K0: fused setup — cbuf rank-1 collapses + fp16 weight transpose ----------------
__global__ __launch_bounds__(256) void k_setup(
    const float* __restrict__ tf_w, const float* __restrict__ tf_b,
    const float* __restrict__ deg_w, const float* __restrict__ deg_b,
    const float* __restrict__ wenc_w, const float* __restrict__ wenc_b,
    const float* __restrict__ comb_w,
    const float* __restrict__ lin_w, const float* __restrict__ Wq,
    const float* __restrict__ Wk, const float* __restrict__ Wv,
    const float* __restrict__ Wsk,
    float* __restrict__ cbuf, _Float16* __restrict__ wt) {
  if (blockIdx.x < 80) {
    const float* Ws[5] = {lin_w, Wq, Wk, Wv, Wsk};
    int idx = blockIdx.x * 256 + threadIdx.x;
    if (idx < 5 * 4096) {
      int s = idx >> 12, r = idx & 4095;
      int j = r >> 6, c = r & 63;
      wt[(s << 12) + c * 64 + j] = (_Float16)Ws[s][j * 64 + c];
    }
  } else if (threadIdx.x < 64) {
    int c = threadIdx.x;
    float A0 = 0, B0 = 0, A1 = 0, B1 = 0, P0 = 0, Q0 = 0, P1 = 0, Q1 = 0;
    for (int j = 0; j < 64; ++j) {
      float w  = wenc_w[j * 64 + c];
      float cw = comb_w[(64 + j) * 64 + c];
      float twj = tf_w[j], tbj = tf_b[j], dwj = deg_w[j], dbj = deg_b[j];
      A0 += twj * w;  B0 += tbj * w;
      A1 += dwj * w;  B1 += dbj * w;
      P0 += twj * cw; Q0 += tbj * cw;
      P1 += dwj * cw; Q1 += dbj * cw;
    }
    float wb = wenc_b[c];
    cbuf[c]       = A0; cbuf[64 + c]  = B0 + wb;
    cbuf[128 + c] = A1; cbuf[192 + c] = B1 + wb;
    cbuf[256 + c] = P0; cbuf[320 + c] = Q0;
    cbuf[384 + c] = P1; cbuf[448 + c] = Q1;
  }
}

// ---------------- K1: MFMA node projections (layouts verified in-session R8) ----------------
__global__ __launch_bounds__(256) void k_node_proj(
    const float* __restrict__ x, const _Float16* __restrict__ wt,
    const float* __restrict__ lin_b, const float* __restrict__ bq,
    const float* __restrict__ bk, const float* __restrict__ bv,
    const float* __restrict__ bsk, const float* __restrict__ be,
    float* __restrict__ q, __half2* __restrict__ kvp,
    float* __restrict__ skipout, int N) {
  __shared__ _Float16 H[4][16 * 72];
  const int tid = threadIdx.x;
  const int lane = tid & 63;
  const int wv = tid >> 6;
  const int mrow = lane & 15;
  const int kgrp = lane >> 4;
  const float invs = 0.17677669529663687f;  // 1/sqrt(32)
  float b_lin[4], b_q[4], b_k[4], b_v[4], b_sk[4];
#pragma unroll
  for (int nt = 0; nt < 4; ++nt) {
    const int cc = nt * 16 + mrow;
    b_lin[nt] = lin_b[cc];
    b_q[nt] = bq[cc];
    b_k[nt] = bk[cc] + be[cc];
    b_v[nt] = bv[cc] + be[cc];
    b_sk[nt] = bsk[cc];
  }
  _Float16* Hw = H[wv];
  const int ntiles = (N + 63) >> 6;
  for (int tile = blockIdx.x; tile < ntiles; tile += gridDim.x) {
    const int base = tile << 6;
    const int rowA = base + wv * 16 + mrow;
    const int rclamp = (rowA < N) ? rowA : (N - 1);
    const float* xr = x + (size_t)rclamp * 64 + kgrp * 8;
    const float4 u0 = *(const float4*)xr;
    const float4 u1 = *(const float4*)(xr + 4);
    const float4 u2 = *(const float4*)(xr + 32);
    const float4 u3 = *(const float4*)(xr + 36);
    const f16x8 a0 = {(_Float16)u0.x, (_Float16)u0.y, (_Float16)u0.z, (_Float16)u0.w,
                      (_Float16)u1.x, (_Float16)u1.y, (_Float16)u1.z, (_Float16)u1.w};
    const f16x8 a1 = {(_Float16)u2.x, (_Float16)u2.y, (_Float16)u2.z, (_Float16)u2.w,
                      (_Float16)u3.x, (_Float16)u3.y, (_Float16)u3.z, (_Float16)u3.w};
#pragma unroll
    for (int nt = 0; nt < 4; ++nt) {
      const _Float16* wb0 = wt + (nt * 16 + mrow) * 64 + kgrp * 8;
      const f16x8 B0 = *(const f16x8*)wb0;
      const f16x8 B1 = *(const f16x8*)(wb0 + 32);
      f32x4 C = {0.f, 0.f, 0.f, 0.f};
      C = __builtin_amdgcn_mfma_f32_16x16x32_f16(a0, B0, C, 0, 0, 0);
      C = __builtin_amdgcn_mfma_f32_16x16x32_f16(a1, B1, C, 0, 0, 0);
#pragma unroll
      for (int r = 0; r < 4; ++r) {
        const float hval = fmaxf(C[r] + b_lin[nt], 0.f);
        Hw[(kgrp * 4 + r) * 72 + nt * 16 + mrow] = (_Float16)hval;
      }
    }
    const f16x8 ha0 = *(const f16x8*)(Hw + mrow * 72 + kgrp * 8);
    const f16x8 ha1 = *(const f16x8*)(Hw + mrow * 72 + 32 + kgrp * 8);
    const int orow0 = base + wv * 16 + kgrp * 4;
#pragma unroll
    for (int nt = 0; nt < 4; ++nt) {
      const _Float16* wb0 = wt + 4096 + (nt * 16 + mrow) * 64 + kgrp * 8;
      const f16x8 B0 = *(const f16x8*)wb0;
      const f16x8 B1 = *(const f16x8*)(wb0 + 32);
      f32x4 C = {0.f, 0.f, 0.f, 0.f};
      C = __builtin_amdgcn_mfma_f32_16x16x32_f16(ha0, B0, C, 0, 0, 0);
      C = __builtin_amdgcn_mfma_f32_16x16x32_f16(ha1, B1, C, 0, 0, 0);
#pragma unroll
      for (int r = 0; r < 4; ++r) {
        const int orow = orow0 + r;
        if (orow < N) q[(size_t)orow * 64 + nt * 16 + mrow] = (C[r] + b_q[nt]) * invs;
      }
    }
#pragma unroll
    for (int nt = 0; nt < 4; ++nt) {
      const _Float16* wk0 = wt + 2 * 4096 + (nt * 16 + mrow) * 64 + kgrp * 8;
      const _Float16* wv0 = wt + 3 * 4096 + (nt * 16 + mrow) * 64 + kgrp * 8;
      const f16x8 Bk0 = *(const f16x8*)wk0;
      const f16x8 Bk1 = *(const f16x8*)(wk0 + 32);
      const f16x8 Bv0 = *(const f16x8*)wv0;
      const f16x8 Bv1 = *(const f16x8*)(wv0 + 32);
      f32x4 Ck = {0.f, 0.f, 0.f, 0.f};
      f32x4 Cv = {0.f, 0.f, 0.f, 0.f};
      Ck = __builtin_amdgcn_mfma_f32_16x16x32_f16(ha0, Bk0, Ck, 0, 0, 0);
      Ck = __builtin_amdgcn_mfma_f32_16x16x32_f16(ha1, Bk1, Ck, 0, 0, 0);
      Cv = __builtin_amdgcn_mfma_f32_16x16x32_f16(ha0, Bv0, Cv, 0, 0, 0);
      Cv = __builtin_amdgcn_mfma_f32_16x16x32_f16(ha1, Bv1, Cv, 0, 0, 0);
#pragma unroll
      for (int r = 0; r < 4; ++r) {
        const int orow = orow0 + r;
        if (orow < N)
          kvp[(size_t)orow * 64 + nt * 16 + mrow] =
              __halves2half2(__float2half_rn(Ck[r] + b_k[nt]), __float2half_rn(Cv[r] + b_v[nt]));
      }
    }
#pragma unroll
    for (int nt = 0; nt < 4; ++nt) {
      const _Float16* wb0 = wt + 4 * 4096 + (nt * 16 + mrow) * 64 + kgrp * 8;
      const f16x8 B0 = *(const f16x8*)wb0;
      const f16x8 B1 = *(const f16x8*)(wb0 + 32);
      f32x4 C = {0.f, 0.f, 0.f, 0.f};
      C = __builtin_amdgcn_mfma_f32_16x16x32_f16(ha0, B0, C, 0, 0, 0);
      C = __builtin_amdgcn_mfma_f32_16x16x32_f16(ha1, B1, C, 0, 0, 0);
#pragma unroll
      for (int r = 0; r < 4; ++r) {
        const int orow = orow0 + r;
        if (orow < N) skipout[(size_t)orow * 64 + nt * 16 + mrow] = C[r] + b_sk[nt];
      }
    }
  }
}

// ---------------- CSR build ----------------
__global__ __launch_bounds__(256) void k_hist(const int* __restrict__ ei, int* __restrict__ counts,
                                              int* __restrict__ rank, int E) {
  int i = blockIdx.x * 256 + threadIdx.x;
  if (i < E) rank[i] = atomicAdd(&counts[ei[E + i]], 1);
}

__global__ __launch_bounds__(256) void k_scan1(const int* __restrict__ counts, int* __restrict__ excl,
                                               int* __restrict__ bsum, int N) {
  __shared__ int s[256];
  const int t = threadIdx.x;
  const int idx = blockIdx.x * 256 + t;
  int val = (idx < N) ? counts[idx] : 0;
  s[t] = val;
  __syncthreads();
  for (int d = 1; d < 256; d <<= 1) {
    int add = (t >= d) ? s[t - d] : 0;
    __syncthreads();
    s[t] += add;
    __syncthreads();
  }
  if (idx < N) excl[idx] = s[t] - val;
  if (t == 255) bsum[blockIdx.x] = s[255];
}

__global__ __launch_bounds__(1024) void k_scan2(int* __restrict__ bsum, int B) {
  __shared__ int sm[1024];
  const int t = threadIdx.x;
  if (B <= 1024) {
    int val = (t < B) ? bsum[t] : 0;
    sm[t] = val;
    __syncthreads();
    for (int d = 1; d < 1024; d <<= 1) {
      int add = (t >= d) ? sm[t - d] : 0;
      __syncthreads();
      sm[t] += add;
      __syncthreads();
    }
    if (t < B) bsum[t] = sm[t] - val;  // exclusive
  } else if (t == 0) {
    int acc = 0;
    for (int i = 0; i < B; ++i) { int tt = bsum[i]; bsum[i] = acc; acc += tt; }
  }
}

__global__ __launch_bounds__(256) void k_scan3(const int* __restrict__ bsum, int* __restrict__ rowptr,
                                               int N, int E) {
  int i = blockIdx.x * 256 + threadIdx.x;
  if (i < N) rowptr[i] = rowptr[i] + bsum[i >> 8];
  if (i == 0) rowptr[N] = E;
}

__global__ __launch_bounds__(256) void k_fill(const int* __restrict__ ei,
                                              const float* __restrict__ node_time,
                                              const float* __restrict__ edge_time,
                                              const int* __restrict__ rowptr,
                                              const int* __restrict__ rank,
                                              int2* __restrict__ er, int E) {
  int e = blockIdx.x * 256 + threadIdx.x;
  if (e < E) {
    int s = ei[e], d = ei[E + e];
    int pos = rowptr[d] + rank[e];
    er[pos] = make_int2(s, __float_as_int(node_time[s] - edge_time[e]));
  }
}

// ---------------- K2: CSR aggregate — R16 body (natural VGPR=76), grid 2048 for tail fill ----------------
__global__ __launch_bounds__(256) void k_aggregate(
    const int* __restrict__ rowptr, const int2* __restrict__ er,
    const float* __restrict__ q, const unsigned* __restrict__ kvu,
    const float* __restrict__ time_w, const float* __restrict__ time_b,
    const float* __restrict__ We,
    float* __restrict__ h1, int N) {
  __shared__ float swS[4][64];
  __shared__ float EAs[4][2][16];
  const int tid = threadIdx.x;
  const int c = tid & 63;
  const int wv = tid >> 6;
  const float INV2PI = 0.15915494309189535f;
  float wcol[32], Gw[32];
#pragma unroll
  for (int j = 0; j < 32; ++j) wcol[j] = We[j * 64 + c];
#pragma unroll
  for (int j = 0; j < 32; ++j) Gw[j] = We[(c & 31) * 64 + (c & 32) + j];
  const float tw = time_w[c & 31] * INV2PI;
  const float tb = time_b[c & 31] * INV2PI;
  const int h32 = c & 32;
  const int lc = c & 15;
  const bool writer = (c & 16) == 0;  // lanes 0-15 (head0) and 32-47 (head1)
  float (*eaF)[16] = EAs[wv];
  const int n0 = blockIdx.x * 4 + wv;
  const int nstride = gridDim.x * 4;
  for (int n = n0; n < N; n += nstride) {
    const int start = __builtin_amdgcn_readfirstlane(rowptr[n]);
    const int end = __builtin_amdgcn_readfirstlane(rowptr[n + 1]);
    const float skipv = h1[(size_t)n * 64 + c];  // prefetch staged skip early
    const float qc = q[(size_t)n * 64 + c];      // pre-scaled by 1/sqrt(32)
    swS[wv][c] = qc;
    float Gc = 0.f;
#pragma unroll
    for (int j = 0; j < 32; ++j) Gc = fmaf(swS[wv][h32 | j], Gw[j], Gc);
    float m = -1e30f, den = 0.f, num = 0.f, S = 0.f;
    for (int ce = start; ce < end; ce += 16) {
      const int cnt = (end - ce < 16) ? (end - ce) : 16;
      // ---- issue phase: 16 er loads + 16 coalesced kv gathers, all in flight ----
      int src_[16];
      float rr_[16];
#pragma unroll
      for (int i = 0; i < 16; ++i) {
        const int ee = ce + ((i < cnt) ? i : cnt - 1);
        const int2 a = er[ee];
        src_[i] = a.x;
        rr_[i] = __int_as_float(a.y);
      }
      unsigned kvr[16];
#pragma unroll
      for (int i = 0; i < 16; ++i) kvr[i] = kvu[(unsigned)(src_[i] * 64 + c)];
      // ---- pass 1: 16 independent partial products + swizzle butterflies ----
      float rv_[16], p[16];
#pragma unroll
      for (int i = 0; i < 16; ++i) {
        float ang = fmaf(rr_[i], tw, tb);
        ang = ang - floorf(ang);
        rv_[i] = __builtin_amdgcn_cosf(ang);   // cos(2*pi*ang)
        const __half2 h2 = *(const __half2*)&kvr[i];
        p[i] = fmaf(rv_[i], Gc, qc * __half2float(h2.x));
      }
#pragma unroll
      for (int i = 0; i < 16; ++i) p[i] = head_sum32(p[i]);
#pragma unroll
      for (int i = 0; i < 16; ++i)
        if (i >= cnt) p[i] = -1e30f;           // mask padded duplicates (-> ea = exact 0)
      // ---- fold chunk max, rescale state once ----
      float cm = p[0];
#pragma unroll
      for (int i = 1; i < 16; ++i) cm = fmaxf(cm, p[i]);
      const float mn = fmaxf(m, cm);
      const float sc = __expf(m - mn);
      num *= sc; den *= sc; S *= sc; m = mn;
      // ---- exp dedup: writer lanes compute ONE exp each (static select), LDS broadcast ----
      if (writer) {
        float pv = p[0];
#pragma unroll
        for (int i = 1; i < 16; ++i) pv = (lc == i) ? p[i] : pv;
        eaF[c >> 5][lc] = __expf(pv - m);
      }
      const float* eah = eaF[h32 ? 1 : 0];
      const float4 e0 = ((const float4*)eah)[0];
      const float4 e1 = ((const float4*)eah)[1];
      const float4 e2 = ((const float4*)eah)[2];
      const float4 e3 = ((const float4*)eah)[3];
      const float ea_[16] = {e0.x, e0.y, e0.z, e0.w, e1.x, e1.y, e1.z, e1.w,
                             e2.x, e2.y, e2.z, e2.w, e3.x, e3.y, e3.z, e3.w};
      // ---- pass 2: branchless accumulate (padded ea are exact zeros) ----
#pragma unroll
      for (int i = 0; i < 16; ++i) {
        const float eai = ea_[i];
        const __half2 h2 = *(const __half2*)&kvr[i];
        num = fmaf(eai, __half2float(h2.y), num);
        S = fmaf(eai, rv_[i], S);
        den += eai;
      }
    }
    // e-projection contribution: econ[c] = sum_j We[j,c] * S[h32 + j]
    swS[wv][c] = S;
    float econ = 0.f;
#pragma unroll
    for (int j = 0; j < 32; ++j) econ = fmaf(swS[wv][h32 | j], wcol[j], econ);
    const float agg = (num + econ) / (den + 1e-16f);
    h1[(size_t)n * 64 + c] = agg + skipv;
  }
}

// ---------------- K4: epilogue (context attention + combine + out + log_softmax) ----------------
__global__ __launch_bounds__(256) void k_epilogue(
    const float* __restrict__ t_int, const float* __restrict__ deg,
    const float* __restrict__ cbuf,
    const float* __restrict__ wx_w, const float* __restrict__ wx_b,
    const float* __restrict__ comb_w, const float* __restrict__ comb_b,
    const float* __restrict__ out_w, const float* __restrict__ out_b,
    const int* __restrict__ y, const unsigned char* __restrict__ maskb,
    float* __restrict__ out, int N) {
  __shared__ float sh[4][64];
  const int tid = threadIdx.x;
  const int c = tid & 63;
  const int wv = tid >> 6;
  float wxreg[64], cbreg[64];
#pragma unroll
  for (int j = 0; j < 64; ++j) { wxreg[j] = wx_w[j * 64 + c]; cbreg[j] = comb_w[j * 64 + c]; }
  const float A0 = cbuf[c], B0 = cbuf[64 + c], A1 = cbuf[128 + c], B1 = cbuf[192 + c];
  const float P0 = cbuf[256 + c], Q0 = cbuf[320 + c], P1 = cbuf[384 + c], Q1 = cbuf[448 + c];
  const float wxb = wx_b[c], cbb = comb_b[c];
  const float ow0 = out_w[c * 2 + 0], ow1 = out_w[c * 2 + 1];
  const float ob0 = out_b[0], ob1 = out_b[1];
  const size_t O1 = (size_t)N * 64;
  const size_t O2 = O1 + (size_t)N * 2;
  const size_t O3 = O2 + (size_t)N;
  const int ngroups = (N + 3) >> 2;
  for (int g = blockIdx.x; g < ngroups; g += gridDim.x) {
    const int n = g * 4 + wv;
    const bool act = n < N;
    float h1a = 0.f, ti = 0.f, dg = 0.f;
    if (act) {
      h1a = out[(size_t)n * 64 + c];
      ti = t_int[n];
      dg = deg[n];
    }
    sh[wv][c] = h1a;
    const float4* hr = (const float4*)&sh[wv][0];
    float xp = wxb;
    float acc = cbb;
#pragma unroll
    for (int j4 = 0; j4 < 16; ++j4) {
      float4 hv = hr[j4];
      xp  = fmaf(hv.x, wxreg[4 * j4 + 0], xp);
      xp  = fmaf(hv.y, wxreg[4 * j4 + 1], xp);
      xp  = fmaf(hv.z, wxreg[4 * j4 + 2], xp);
      xp  = fmaf(hv.w, wxreg[4 * j4 + 3], xp);
      acc = fmaf(hv.x, cbreg[4 * j4 + 0], acc);
      acc = fmaf(hv.y, cbreg[4 * j4 + 1], acc);
      acc = fmaf(hv.z, cbreg[4 * j4 + 2], acc);
      acc = fmaf(hv.w, cbreg[4 * j4 + 3], acc);
    }
    xp = tanhf(xp);
    const float ep0 = tanhf(fmaf(ti, A0, B0));
    const float ep1 = tanhf(fmaf(dg, A1, B1));
    float d0 = ep0 * xp, d1 = ep1 * xp;
#pragma unroll
    for (int msk = 32; msk >= 1; msk >>= 1) { d0 += __shfl_xor(d0, msk, 64); d1 += __shfl_xor(d1, msk, 64); }
    const float mx = fmaxf(d0, d1);
    const float e0 = expf(d0 - mx), e1 = expf(d1 - mx);
    const float sden = e0 + e1;
    const float s0 = e0 / sden, s1 = e1 / sden;
    acc = fmaf(s0, fmaf(ti, P0, Q0), acc);
    acc = fmaf(s1, fmaf(dg, P1, Q1), acc);
    float z0 = acc * ow0, z1 = acc * ow1;
#pragma unroll
    for (int msk = 32; msk >= 1; msk >>= 1) { z0 += __shfl_xor(z0, msk, 64); z1 += __shfl_xor(z1, msk, 64); }
    if (act) {
      out[(size_t)n * 64 + c] = acc;
      if (c == 0) {
        z0 += ob0; z1 += ob1;
        const float mz = fmaxf(z0, z1);
        const float lse = mz + logf(expf(z0 - mz) + expf(z1 - mz));
        out[O1 + (size_t)n * 2 + 0] = z0 - lse;
        out[O1 + (size_t)n * 2 + 1] = z1 - lse;
        out[O2 + (size_t)n] = (float)y[n];
        out[O3 + (size_t)n] = mask_val(maskb, n);
      }
    }
  }
}

extern "C" void kernel_launch(void* const* d_in, const int* in_sizes, int n_in,
                              void* d_out, int out_size, void* d_ws, size_t ws_size,
                              hipStream_t stream) {
  const float* x          = (const float*)d_in[0];
  const int*   ei         = (const int*)d_in[1];
  const float* node_time  = (const float*)d_in[2];
  const float* edge_time  = (const float*)d_in[3];
  const float* nmoti      = (const float*)d_in[4];
  const float* nod        = (const float*)d_in[5];
  const int*   y          = (const int*)d_in[6];
  const unsigned char* mask = (const unsigned char*)d_in[7];
  const float* time_w = (const float*)d_in[8];
  const float* time_b = (const float*)d_in[9];
  const float* tf_w   = (const float*)d_in[10];
  const float* tf_b   = (const float*)d_in[11];
  const float* deg_w  = (const float*)d_in[12];
  const float* deg_b  = (const float*)d_in[13];
  const float* lin_w  = (const float*)d_in[14];
  const float* lin_b  = (const float*)d_in[15];
  const float* Wq     = (const float*)d_in[16];
  const float* bq     = (const float*)d_in[17];
  const float* Wk     = (const float*)d_in[18];
  const float* bk     = (const float*)d_in[19];
  const float* Wv     = (const float*)d_in[20];
  const float* bv     = (const float*)d_in[21];
  const float* We     = (const float*)d_in[22];
  const float* be     = (const float*)d_in[23];
  const float* Wsk    = (const float*)d_in[24];
  const float* bsk    = (const float*)d_in[25];
  const float* wenc_w = (const float*)d_in[26];
  const float* wenc_b = (const float*)d_in[27];
  const float* wx_w   = (const float*)d_in[28];
  const float* wx_b   = (const float*)d_in[29];
  const float* comb_w = (const float*)d_in[30];
  const float* comb_b = (const float*)d_in[31];
  const float* out_w  = (const float*)d_in[32];
  const float* out_b  = (const float*)d_in[33];

  const int N = in_sizes[2];   // node_time
  const int E = in_sizes[3];   // edge_time
  const size_t N64 = (size_t)N * 64;

  float*    q    = (float*)d_ws;
  __half2*  kvp  = (__half2*)(q + N64);       // N64 half2 = N64 * 4B
  int2*     er   = (int2*)((char*)kvp + N64 * sizeof(__half2));
  int*      rank = (int*)(er + E);            // E ints
  int*      counts = rank + E;
  int*      rowptr = counts + N;              // N+1 ints
  int*      bsum   = rowptr + N + 1;          // ceil(N/256) ints (padded)
  float*    cbuf   = (float*)(bsum + 4096);
  _Float16* wt     = (_Float16*)(cbuf + 512); // 5 * 4096 fp16
  float*    outf   = (float*)d_out;
  float*    skip   = outf;  // stage skip in d_out[0:N*64)

  const int B = (N + 255) / 256;

  hipMemsetAsync(counts, 0, (size_t)N * sizeof(int), stream);

  k_setup<<<81, 256, 0, stream>>>(tf_w, tf_b, deg_w, deg_b, wenc_w, wenc_b, comb_w,
                                  lin_w, Wq, Wk, Wv, Wsk, cbuf, wt);

  const int ntiles = (N + 63) >> 6;
  k_node_proj<<<ntiles, 256, 0, stream>>>(x, wt, lin_b, bq, bk, bv, bsk, be,
                                          q, kvp, skip, N);

  const int EB = (E + 255) / 256;
  k_hist<<<EB, 256, 0, stream>>>(ei, counts, rank, E);
  k_scan1<<<B, 256, 0, stream>>>(counts, rowptr, bsum, N);
  k_scan2<<<1, 1024, 0, stream>>>(bsum, B);
  k_scan3<<<B, 256, 0, stream>>>(bsum, rowptr, N, E);
  k_fill<<<EB, 256, 0, stream>>>(ei, node_time, edge_time, rowptr, rank, er, E);

  // persistent grid: 2048 blocks; residency 6 blocks/CU (natural VGPR=76), extra blocks
  // backfill as early finishers retire (tail smoothing, no resource change)
  int agb = 2048;
  if (agb > (N + 3) / 4) agb = (N + 3) / 4;
  k_aggregate<<<agb, 256, 0, stream>>>(rowptr, er, q, (const unsigned*)kvp,
                                       time_w, time_b, We, outf, N);

  k_epilogue<<<2048, 256, 0, stream>>>(nmoti, nod, cbuf, wx_w, wx_b,
                                       comb_w, comb_b, out_w, out_b, y, mask, outf, N);
}

// Round 19
// 351.361 us; speedup vs baseline: 1.7810x; 1.0186x over previous
//
#include <hip/hip_runtime.h>
#include <hip/hip_fp16.h>

#define DEV __device__ __forceinline__

typedef _Float16 f16x8 __attribute__((ext_vector_type(8)));
typedef float f32x4 __attribute__((ext_vector_type(4)));

DEV float mask_val(const unsigned char* mb, int n) {
  // Detect train_mask storage from its first element: uint8 bool / int32 / float32.
  unsigned b0 = mb[0], b1 = mb[1], b2 = mb[2], b3 = mb[3];
  if (b0 <= 1u && b1 == b0 && b2 == b0 && b3 == b0) {
    return mb[n] ? 1.f : 0.f;                       // 1-byte bool
  } else if (b1 == 0u && b2 == 0u && b3 == 0u) {
    return ((const int*)mb)[n] ? 1.f : 0.f;         // int32
  } else {
    return (((const float*)mb)[n] != 0.f) ? 1.f : 0.f; // float32
  }
}

// butterfly sum across each 32-lane half via ds_swizzle (LDS pipe — overlaps the busy VALU)
DEV float head_sum32(float x) {
  x += __int_as_float(__builtin_amdgcn_ds_swizzle(__float_as_int(x), 0x041F));  // xor 1
  x += __int_as_float(__builtin_amdgcn_ds_swizzle(__float_as_int(x), 0x081F));  // xor 2
  x += __int_as_float(__builtin_amdgcn_ds_swizzle(__float_as_int(x), 0x101F));  // xor 4
  x += __int_as_float(__builtin_amdgcn_ds_swizzle(__float_as_int(x), 0x201F));  // xor 8
  x += __int_as_float(__builtin_amdgcn_ds_swizzle(__float_as_int(x), 0x401F));  // xor 16
  return x;
}

// ---------------- K0: fused setup — weight transpose + cbuf collapses + counts zeroing ----------------
__global__ __launch_bounds__(256) void k_setup(
    const float* __restrict__ tf_w, const float* __restrict__ tf_b,
    const float* __restrict__ deg_w, const float* __restrict__ deg_b,
    const float* __restrict__ wenc_w, const float* __restrict__ wenc_b,
    const float* __restrict__ comb_w,
    const float* __restrict__ lin_w, const float* __restrict__ Wq,
    const float* __restrict__ Wk, const float* __restrict__ Wv,
    const float* __restrict__ Wsk,
    float* __restrict__ cbuf, _Float16* __restrict__ wt,
    int* __restrict__ counts, int N) {
  const int bid = blockIdx.x;
  if (bid < 80) {
    const float* Ws[5] = {lin_w, Wq, Wk, Wv, Wsk};
    int idx = bid * 256 + threadIdx.x;
    if (idx < 5 * 4096) {
      int s = idx >> 12, r = idx & 4095;
      int j = r >> 6, c = r & 63;
      wt[(s << 12) + c * 64 + j] = (_Float16)Ws[s][j * 64 + c];
    }
  } else if (bid == 80) {
    if (threadIdx.x < 64) {
      int c = threadIdx.x;
      float A0 = 0, B0 = 0, A1 = 0, B1 = 0, P0 = 0, Q0 = 0, P1 = 0, Q1 = 0;
      for (int j = 0; j < 64; ++j) {
        float w  = wenc_w[j * 64 + c];
        float cw = comb_w[(64 + j) * 64 + c];
        float twj = tf_w[j], tbj = tf_b[j], dwj = deg_w[j], dbj = deg_b[j];
        A0 += twj * w;  B0 += tbj * w;
        A1 += dwj * w;  B1 += dbj * w;
        P0 += twj * cw; Q0 += tbj * cw;
        P1 += dwj * cw; Q1 += dbj * cw;
      }
      float wb = wenc_b[c];
      cbuf[c]       = A0; cbuf[64 + c]  = B0 + wb;
      cbuf[128 + c] = A1; cbuf[192 + c] = B1 + wb;
      cbuf[256 + c] = P0; cbuf[320 + c] = Q0;
      cbuf[384 + c] = P1; cbuf[448 + c] = Q1;
    }
  } else {
    const int i = (bid - 81) * 256 + threadIdx.x;
    if (i < N) counts[i] = 0;
  }
}

// ---------------- K1: MFMA node projections FUSED with edge histogram ----------------
// Blocks [0, ntiles): projection tile per block (MFMA path, R8-verified layouts).
// Blocks [ntiles, ntiles+EB): k_hist chunks — independent work, runs CONCURRENTLY,
// hidden under the projection kernel's latency slack.
__global__ __launch_bounds__(256) void k_node_proj(
    const float* __restrict__ x, const _Float16* __restrict__ wt,
    const float* __restrict__ lin_b, const float* __restrict__ bq,
    const float* __restrict__ bk, const float* __restrict__ bv,
    const float* __restrict__ bsk, const float* __restrict__ be,
    float* __restrict__ q, __half2* __restrict__ kvp,
    float* __restrict__ skipout, int N,
    const int* __restrict__ ei, int* __restrict__ counts,
    int* __restrict__ rank, int E, int ntiles) {
  __shared__ _Float16 H[4][16 * 72];
  const int bid = blockIdx.x;
  const int tid = threadIdx.x;
  if (bid >= ntiles) {
    // ---- hist path ----
    const int i = (bid - ntiles) * 256 + tid;
    if (i < E) rank[i] = atomicAdd(&counts[ei[E + i]], 1);
    return;
  }
  const int lane = tid & 63;
  const int wv = tid >> 6;
  const int mrow = lane & 15;
  const int kgrp = lane >> 4;
  const float invs = 0.17677669529663687f;  // 1/sqrt(32)
  float b_lin[4], b_q[4], b_k[4], b_v[4], b_sk[4];
#pragma unroll
  for (int nt = 0; nt < 4; ++nt) {
    const int cc = nt * 16 + mrow;
    b_lin[nt] = lin_b[cc];
    b_q[nt] = bq[cc];
    b_k[nt] = bk[cc] + be[cc];
    b_v[nt] = bv[cc] + be[cc];
    b_sk[nt] = bsk[cc];
  }
  _Float16* Hw = H[wv];
  const int base = bid << 6;
  const int rowA = base + wv * 16 + mrow;
  const int rclamp = (rowA < N) ? rowA : (N - 1);
  const float* xr = x + (size_t)rclamp * 64 + kgrp * 8;
  const float4 u0 = *(const float4*)xr;
  const float4 u1 = *(const float4*)(xr + 4);
  const float4 u2 = *(const float4*)(xr + 32);
  const float4 u3 = *(const float4*)(xr + 36);
  const f16x8 a0 = {(_Float16)u0.x, (_Float16)u0.y, (_Float16)u0.z, (_Float16)u0.w,
                    (_Float16)u1.x, (_Float16)u1.y, (_Float16)u1.z, (_Float16)u1.w};
  const f16x8 a1 = {(_Float16)u2.x, (_Float16)u2.y, (_Float16)u2.z, (_Float16)u2.w,
                    (_Float16)u3.x, (_Float16)u3.y, (_Float16)u3.z, (_Float16)u3.w};
#pragma unroll
  for (int nt = 0; nt < 4; ++nt) {
    const _Float16* wb0 = wt + (nt * 16 + mrow) * 64 + kgrp * 8;
    const f16x8 B0 = *(const f16x8*)wb0;
    const f16x8 B1 = *(const f16x8*)(wb0 + 32);
    f32x4 C = {0.f, 0.f, 0.f, 0.f};
    C = __builtin_amdgcn_mfma_f32_16x16x32_f16(a0, B0, C, 0, 0, 0);
    C = __builtin_amdgcn_mfma_f32_16x16x32_f16(a1, B1, C, 0, 0, 0);
#pragma unroll
    for (int r = 0; r < 4; ++r) {
      const float hval = fmaxf(C[r] + b_lin[nt], 0.f);
      Hw[(kgrp * 4 + r) * 72 + nt * 16 + mrow] = (_Float16)hval;
    }
  }
  const f16x8 ha0 = *(const f16x8*)(Hw + mrow * 72 + kgrp * 8);
  const f16x8 ha1 = *(const f16x8*)(Hw + mrow * 72 + 32 + kgrp * 8);
  const int orow0 = base + wv * 16 + kgrp * 4;
#pragma unroll
  for (int nt = 0; nt < 4; ++nt) {
    const _Float16* wb0 = wt + 4096 + (nt * 16 + mrow) * 64 + kgrp * 8;
    const f16x8 B0 = *(const f16x8*)wb0;
    const f16x8 B1 = *(const f16x8*)(wb0 + 32);
    f32x4 C = {0.f, 0.f, 0.f, 0.f};
    C = __builtin_amdgcn_mfma_f32_16x16x32_f16(ha0, B0, C, 0, 0, 0);
    C = __builtin_amdgcn_mfma_f32_16x16x32_f16(ha1, B1, C, 0, 0, 0);
#pragma unroll
    for (int r = 0; r < 4; ++r) {
      const int orow = orow0 + r;
      if (orow < N) q[(size_t)orow * 64 + nt * 16 + mrow] = (C[r] + b_q[nt]) * invs;
    }
  }
#pragma unroll
  for (int nt = 0; nt < 4; ++nt) {
    const _Float16* wk0 = wt + 2 * 4096 + (nt * 16 + mrow) * 64 + kgrp * 8;
    const _Float16* wv0 = wt + 3 * 4096 + (nt * 16 + mrow) * 64 + kgrp * 8;
    const f16x8 Bk0 = *(const f16x8*)wk0;
    const f16x8 Bk1 = *(const f16x8*)(wk0 + 32);
    const f16x8 Bv0 = *(const f16x8*)wv0;
    const f16x8 Bv1 = *(const f16x8*)(wv0 + 32);
    f32x4 Ck = {0.f, 0.f, 0.f, 0.f};
    f32x4 Cv = {0.f, 0.f, 0.f, 0.f};
    Ck = __builtin_amdgcn_mfma_f32_16x16x32_f16(ha0, Bk0, Ck, 0, 0, 0);
    Ck = __builtin_amdgcn_mfma_f32_16x16x32_f16(ha1, Bk1, Ck, 0, 0, 0);
    Cv = __builtin_amdgcn_mfma_f32_16x16x32_f16(ha0, Bv0, Cv, 0, 0, 0);
    Cv = __builtin_amdgcn_mfma_f32_16x16x32_f16(ha1, Bv1, Cv, 0, 0, 0);
#pragma unroll
    for (int r = 0; r < 4; ++r) {
      const int orow = orow0 + r;
      if (orow < N)
        kvp[(size_t)orow * 64 + nt * 16 + mrow] =
            __halves2half2(__float2half_rn(Ck[r] + b_k[nt]), __float2half_rn(Cv[r] + b_v[nt]));
    }
  }
#pragma unroll
  for (int nt = 0; nt < 4; ++nt) {
    const _Float16* wb0 = wt + 4 * 4096 + (nt * 16 + mrow) * 64 + kgrp * 8;
    const f16x8 B0 = *(const f16x8*)wb0;
    const f16x8 B1 = *(const f16x8*)(wb0 + 32);
    f32x4 C = {0.f, 0.f, 0.f, 0.f};
    C = __builtin_amdgcn_mfma_f32_16x16x32_f16(ha0, B0, C, 0, 0, 0);
    C = __builtin_amdgcn_mfma_f32_16x16x32_f16(ha1, B1, C, 0, 0, 0);
#pragma unroll
    for (int r = 0; r < 4; ++r) {
      const int orow = orow0 + r;
      if (orow < N) skipout[(size_t)orow * 64 + nt * 16 + mrow] = C[r] + b_sk[nt];
    }
  }
}

// ---------------- CSR scan + fill ----------------
__global__ __launch_bounds__(256) void k_scan1(const int* __restrict__ counts, int* __restrict__ excl,
                                               int* __restrict__ bsum, int N) {
  __shared__ int s[256];
  const int t = threadIdx.x;
  const int idx = blockIdx.x * 256 + t;
  int val = (idx < N) ? counts[idx] : 0;
  s[t] = val;
  __syncthreads();
  for (int d = 1; d < 256; d <<= 1) {
    int add = (t >= d) ? s[t - d] : 0;
    __syncthreads();
    s[t] += add;
    __syncthreads();
  }
  if (idx < N) excl[idx] = s[t] - val;
  if (t == 255) bsum[blockIdx.x] = s[255];
}

__global__ __launch_bounds__(1024) void k_scan2(int* __restrict__ bsum, int B) {
  __shared__ int sm[1024];
  const int t = threadIdx.x;
  if (B <= 1024) {
    int val = (t < B) ? bsum[t] : 0;
    sm[t] = val;
    __syncthreads();
    for (int d = 1; d < 1024; d <<= 1) {
      int add = (t >= d) ? sm[t - d] : 0;
      __syncthreads();
      sm[t] += add;
      __syncthreads();
    }
    if (t < B) bsum[t] = sm[t] - val;  // exclusive
  } else if (t == 0) {
    int acc = 0;
    for (int i = 0; i < B; ++i) { int tt = bsum[i]; bsum[i] = acc; acc += tt; }
  }
}

__global__ __launch_bounds__(256) void k_scan3(const int* __restrict__ bsum, int* __restrict__ rowptr,
                                               int N, int E) {
  int i = blockIdx.x * 256 + threadIdx.x;
  if (i < N) rowptr[i] = rowptr[i] + bsum[i >> 8];
  if (i == 0) rowptr[N] = E;
}

__global__ __launch_bounds__(256) void k_fill(const int* __restrict__ ei,
                                              const float* __restrict__ node_time,
                                              const float* __restrict__ edge_time,
                                              const int* __restrict__ rowptr,
                                              const int* __restrict__ rank,
                                              int2* __restrict__ er, int E) {
  int e = blockIdx.x * 256 + threadIdx.x;
  if (e < E) {
    int s = ei[e], d = ei[E + e];
    int pos = rowptr[d] + rank[e];
    er[pos] = make_int2(s, __float_as_int(node_time[s] - edge_time[e]));
  }
}

// ---------------- K2: CSR aggregate — R16 body (natural VGPR=76), grid 2048 ----------------
__global__ __launch_bounds__(256) void k_aggregate(
    const int* __restrict__ rowptr, const int2* __restrict__ er,
    const float* __restrict__ q, const unsigned* __restrict__ kvu,
    const float* __restrict__ time_w, const float* __restrict__ time_b,
    const float* __restrict__ We,
    float* __restrict__ h1, int N) {
  __shared__ float swS[4][64];
  __shared__ float EAs[4][2][16];
  const int tid = threadIdx.x;
  const int c = tid & 63;
  const int wv = tid >> 6;
  const float INV2PI = 0.15915494309189535f;
  float wcol[32], Gw[32];
#pragma unroll
  for (int j = 0; j < 32; ++j) wcol[j] = We[j * 64 + c];
#pragma unroll
  for (int j = 0; j < 32; ++j) Gw[j] = We[(c & 31) * 64 + (c & 32) + j];
  const float tw = time_w[c & 31] * INV2PI;
  const float tb = time_b[c & 31] * INV2PI;
  const int h32 = c & 32;
  const int lc = c & 15;
  const bool writer = (c & 16) == 0;  // lanes 0-15 (head0) and 32-47 (head1)
  float (*eaF)[16] = EAs[wv];
  const int n0 = blockIdx.x * 4 + wv;
  const int nstride = gridDim.x * 4;
  for (int n = n0; n < N; n += nstride) {
    const int start = __builtin_amdgcn_readfirstlane(rowptr[n]);
    const int end = __builtin_amdgcn_readfirstlane(rowptr[n + 1]);
    const float skipv = h1[(size_t)n * 64 + c];  // prefetch staged skip early
    const float qc = q[(size_t)n * 64 + c];      // pre-scaled by 1/sqrt(32)
    swS[wv][c] = qc;
    float Gc = 0.f;
#pragma unroll
    for (int j = 0; j < 32; ++j) Gc = fmaf(swS[wv][h32 | j], Gw[j], Gc);
    float m = -1e30f, den = 0.f, num = 0.f, S = 0.f;
    for (int ce = start; ce < end; ce += 16) {
      const int cnt = (end - ce < 16) ? (end - ce) : 16;
      // ---- issue phase: 16 er loads + 16 coalesced kv gathers, all in flight ----
      int src_[16];
      float rr_[16];
#pragma unroll
      for (int i = 0; i < 16; ++i) {
        const int ee = ce + ((i < cnt) ? i : cnt - 1);
        const int2 a = er[ee];
        src_[i] = a.x;
        rr_[i] = __int_as_float(a.y);
      }
      unsigned kvr[16];
#pragma unroll
      for (int i = 0; i < 16; ++i) kvr[i] = kvu[(unsigned)(src_[i] * 64 + c)];
      // ---- pass 1: 16 independent partial products + swizzle butterflies ----
      float rv_[16], p[16];
#pragma unroll
      for (int i = 0; i < 16; ++i) {
        float ang = fmaf(rr_[i], tw, tb);
        ang = ang - floorf(ang);
        rv_[i] = __builtin_amdgcn_cosf(ang);   // cos(2*pi*ang)
        const __half2 h2 = *(const __half2*)&kvr[i];
        p[i] = fmaf(rv_[i], Gc, qc * __half2float(h2.x));
      }
#pragma unroll
      for (int i = 0; i < 16; ++i) p[i] = head_sum32(p[i]);
#pragma unroll
      for (int i = 0; i < 16; ++i)
        if (i >= cnt) p[i] = -1e30f;           // mask padded duplicates (-> ea = exact 0)
      // ---- fold chunk max, rescale state once ----
      float cm = p[0];
#pragma unroll
      for (int i = 1; i < 16; ++i) cm = fmaxf(cm, p[i]);
      const float mn = fmaxf(m, cm);
      const float sc = __expf(m - mn);
      num *= sc; den *= sc; S *= sc; m = mn;
      // ---- exp dedup: writer lanes compute ONE exp each (static select), LDS broadcast ----
      if (writer) {
        float pv = p[0];
#pragma unroll
        for (int i = 1; i < 16; ++i) pv = (lc == i) ? p[i] : pv;
        eaF[c >> 5][lc] = __expf(pv - m);
      }
      const float* eah = eaF[h32 ? 1 : 0];
      const float4 e0 = ((const float4*)eah)[0];
      const float4 e1 = ((const float4*)eah)[1];
      const float4 e2 = ((const float4*)eah)[2];
      const float4 e3 = ((const float4*)eah)[3];
      const float ea_[16] = {e0.x, e0.y, e0.z, e0.w, e1.x, e1.y, e1.z, e1.w,
                             e2.x, e2.y, e2.z, e2.w, e3.x, e3.y, e3.z, e3.w};
      // ---- pass 2: branchless accumulate (padded ea are exact zeros) ----
#pragma unroll
      for (int i = 0; i < 16; ++i) {
        const float eai = ea_[i];
        const __half2 h2 = *(const __half2*)&kvr[i];
        num = fmaf(eai, __half2float(h2.y), num);
        S = fmaf(eai, rv_[i], S);
        den += eai;
      }
    }
    // e-projection contribution: econ[c] = sum_j We[j,c] * S[h32 + j]
    swS[wv][c] = S;
    float econ = 0.f;
#pragma unroll
    for (int j = 0; j < 32; ++j) econ = fmaf(swS[wv][h32 | j], wcol[j], econ);
    const float agg = (num + econ) / (den + 1e-16f);
    h1[(size_t)n * 64 + c] = agg + skipv;
  }
}

// ---------------- K4: epilogue (context attention + combine + out + log_softmax) ----------------
__global__ __launch_bounds__(256) void k_epilogue(
    const float* __restrict__ t_int, const float* __restrict__ deg,
    const float* __restrict__ cbuf,
    const float* __restrict__ wx_w, const float* __restrict__ wx_b,
    const float* __restrict__ comb_w, const float* __restrict__ comb_b,
    const float* __restrict__ out_w, const float* __restrict__ out_b,
    const int* __restrict__ y, const unsigned char* __restrict__ maskb,
    float* __restrict__ out, int N) {
  __shared__ float sh[4][64];
  const int tid = threadIdx.x;
  const int c = tid & 63;
  const int wv = tid >> 6;
  float wxreg[64], cbreg[64];
#pragma unroll
  for (int j = 0; j < 64; ++j) { wxreg[j] = wx_w[j * 64 + c]; cbreg[j] = comb_w[j * 64 + c]; }
  const float A0 = cbuf[c], B0 = cbuf[64 + c], A1 = cbuf[128 + c], B1 = cbuf[192 + c];
  const float P0 = cbuf[256 + c], Q0 = cbuf[320 + c], P1 = cbuf[384 + c], Q1 = cbuf[448 + c];
  const float wxb = wx_b[c], cbb = comb_b[c];
  const float ow0 = out_w[c * 2 + 0], ow1 = out_w[c * 2 + 1];
  const float ob0 = out_b[0], ob1 = out_b[1];
  const size_t O1 = (size_t)N * 64;
  const size_t O2 = O1 + (size_t)N * 2;
  const size_t O3 = O2 + (size_t)N;
  const int ngroups = (N + 3) >> 2;
  for (int g = blockIdx.x; g < ngroups; g += gridDim.x) {
    const int n = g * 4 + wv;
    const bool act = n < N;
    float h1a = 0.f, ti = 0.f, dg = 0.f;
    if (act) {
      h1a = out[(size_t)n * 64 + c];
      ti = t_int[n];
      dg = deg[n];
    }
    sh[wv][c] = h1a;
    const float4* hr = (const float4*)&sh[wv][0];
    float xp = wxb;
    float acc = cbb;
#pragma unroll
    for (int j4 = 0; j4 < 16; ++j4) {
      float4 hv = hr[j4];
      xp  = fmaf(hv.x, wxreg[4 * j4 + 0], xp);
      xp  = fmaf(hv.y, wxreg[4 * j4 + 1], xp);
      xp  = fmaf(hv.z, wxreg[4 * j4 + 2], xp);
      xp  = fmaf(hv.w, wxreg[4 * j4 + 3], xp);
      acc = fmaf(hv.x, cbreg[4 * j4 + 0], acc);
      acc = fmaf(hv.y, cbreg[4 * j4 + 1], acc);
      acc = fmaf(hv.z, cbreg[4 * j4 + 2], acc);
      acc = fmaf(hv.w, cbreg[4 * j4 + 3], acc);
    }
    xp = tanhf(xp);
    const float ep0 = tanhf(fmaf(ti, A0, B0));
    const float ep1 = tanhf(fmaf(dg, A1, B1));
    float d0 = ep0 * xp, d1 = ep1 * xp;
#pragma unroll
    for (int msk = 32; msk >= 1; msk >>= 1) { d0 += __shfl_xor(d0, msk, 64); d1 += __shfl_xor(d1, msk, 64); }
    const float mx = fmaxf(d0, d1);
    const float e0 = expf(d0 - mx), e1 = expf(d1 - mx);
    const float sden = e0 + e1;
    const float s0 = e0 / sden, s1 = e1 / sden;
    acc = fmaf(s0, fmaf(ti, P0, Q0), acc);
    acc = fmaf(s1, fmaf(dg, P1, Q1), acc);
    float z0 = acc * ow0, z1 = acc * ow1;
#pragma unroll
    for (int msk = 32; msk >= 1; msk >>= 1) { z0 += __shfl_xor(z0, msk, 64); z1 += __shfl_xor(z1, msk, 64); }
    if (act) {
      out[(size_t)n * 64 + c] = acc;
      if (c == 0) {
        z0 += ob0; z1 += ob1;
        const float mz = fmaxf(z0, z1);
        const float lse = mz + logf(expf(z0 - mz) + expf(z1 - mz));
        out[O1 + (size_t)n * 2 + 0] = z0 - lse;
        out[O1 + (size_t)n * 2 + 1] = z1 - lse;
        out[O2 + (size_t)n] = (float)y[n];
        out[O3 + (size_t)n] = mask_val(maskb, n);
      }
    }
  }
}

extern "C" void kernel_launch(void* const* d_in, const int* in_sizes, int n_in,
                              void* d_out, int out_size, void* d_ws, size_t ws_size,
                              hipStream_t stream) {
  const float* x          = (const float*)d_in[0];
  const int*   ei         = (const int*)d_in[1];
  const float* node_time  = (const float*)d_in[2];
  const float* edge_time  = (const float*)d_in[3];
  const float* nmoti      = (const float*)d_in[4];
  const float* nod        = (const float*)d_in[5];
  const int*   y          = (const int*)d_in[6];
  const unsigned char* mask = (const unsigned char*)d_in[7];
  const float* time_w = (const float*)d_in[8];
  const float* time_b = (const float*)d_in[9];
  const float* tf_w   = (const float*)d_in[10];
  const float* tf_b   = (const float*)d_in[11];
  const float* deg_w  = (const float*)d_in[12];
  const float* deg_b  = (const float*)d_in[13];
  const float* lin_w  = (const float*)d_in[14];
  const float* lin_b  = (const float*)d_in[15];
  const float* Wq     = (const float*)d_in[16];
  const float* bq     = (const float*)d_in[17];
  const float* Wk     = (const float*)d_in[18];
  const float* bk     = (const float*)d_in[19];
  const float* Wv     = (const float*)d_in[20];
  const float* bv     = (const float*)d_in[21];
  const float* We     = (const float*)d_in[22];
  const float* be     = (const float*)d_in[23];
  const float* Wsk    = (const float*)d_in[24];
  const float* bsk    = (const float*)d_in[25];
  const float* wenc_w = (const float*)d_in[26];
  const float* wenc_b = (const float*)d_in[27];
  const float* wx_w   = (const float*)d_in[28];
  const float* wx_b   = (const float*)d_in[29];
  const float* comb_w = (const float*)d_in[30];
  const float* comb_b = (const float*)d_in[31];
  const float* out_w  = (const float*)d_in[32];
  const float* out_b  = (const float*)d_in[33];

  const int N = in_sizes[2];   // node_time
  const int E = in_sizes[3];   // edge_time
  const size_t N64 = (size_t)N * 64;

  float*    q    = (float*)d_ws;
  __half2*  kvp  = (__half2*)(q + N64);       // N64 half2 = N64 * 4B
  int2*     er   = (int2*)((char*)kvp + N64 * sizeof(__half2));
  int*      rank = (int*)(er + E);            // E ints
  int*      counts = rank + E;
  int*      rowptr = counts + N;              // N+1 ints
  int*      bsum   = rowptr + N + 1;          // ceil(N/256) ints (padded)
  float*    cbuf   = (float*)(bsum + 4096);
  _Float16* wt     = (_Float16*)(cbuf + 512); // 5 * 4096 fp16
  float*    outf   = (float*)d_out;
  float*    skip   = outf;  // stage skip in d_out[0:N*64)

  const int B = (N + 255) / 256;
  const int ntiles = (N + 63) >> 6;
  const int EB = (E + 255) / 256;

  // setup: 80 wt-convert blocks + 1 cbuf block + B counts-zero blocks (replaces memset)
  k_setup<<<81 + B, 256, 0, stream>>>(tf_w, tf_b, deg_w, deg_b, wenc_w, wenc_b, comb_w,
                                      lin_w, Wq, Wk, Wv, Wsk, cbuf, wt, counts, N);

  // node projections FUSED with edge histogram (independent work, concurrent)
  k_node_proj<<<ntiles + EB, 256, 0, stream>>>(x, wt, lin_b, bq, bk, bv, bsk, be,
                                               q, kvp, skip, N, ei, counts, rank, E, ntiles);

  k_scan1<<<B, 256, 0, stream>>>(counts, rowptr, bsum, N);
  k_scan2<<<1, 1024, 0, stream>>>(bsum, B);
  k_scan3<<<B, 256, 0, stream>>>(bsum, rowptr, N, E);
  k_fill<<<EB, 256, 0, stream>>>(ei, node_time, edge_time, rowptr, rank, er, E);

  // persistent grid: 2048 blocks (6 resident blocks/CU at natural VGPR=76 + backfill)
  int agb = 2048;
  if (agb > (N + 3) / 4) agb = (N + 3) / 4;
  k_aggregate<<<agb, 256, 0, stream>>>(rowptr, er, q, (const unsigned*)kvp,
                                       time_w, time_b, We, outf, N);

  k_epilogue<<<2048, 256, 0, stream>>>(nmoti, nod, cbuf, wx_w, wx_b,
                                       comb_w, comb_b, out_w, out_b, y, mask, outf, N);
}